// Round 2
// baseline (3343.201 us; speedup 1.0000x reference)
//
#include <hip/hip_runtime.h>

// Problem constants (DecoderLSTMAttn): B=256, L=24, R=49, F=2048, E=256, H=512, A=512, V=10000
constexpr int Bc = 256, Lc = 24, Rc = 49, Fc = 2048, Ec = 256, Hc = 512, Acn = 512, Vc = 10000;
constexpr int STEPS = Lc - 1;           // 23
constexpr int XK = Ec + Fc + Hc;        // 2816: x = [emb | ctx | h]

using bf16x8  = __attribute__((ext_vector_type(8))) __bf16;
using floatx4 = __attribute__((ext_vector_type(4))) float;
using ushort8 = __attribute__((ext_vector_type(8))) unsigned short;
using ushort4v = __attribute__((ext_vector_type(4))) unsigned short;

__device__ inline float bf2f(unsigned short u) {
    unsigned int x = ((unsigned int)u) << 16;
    float f; __builtin_memcpy(&f, &x, sizeof(f)); return f;
}
__device__ inline unsigned short f2bf(float f) {
    unsigned int u; __builtin_memcpy(&u, &f, sizeof(u));
    u += 0x7fffu + ((u >> 16) & 1u);
    return (unsigned short)(u >> 16);
}

// ---------------------------------------------------------------------------
// fp32 -> bf16 bulk convert (n must be a multiple of 4; all our tensors are)
// ---------------------------------------------------------------------------
__global__ __launch_bounds__(256) void convert_f2b(
    const float* __restrict__ src, unsigned short* __restrict__ dst, int n4)
{
    int i = blockIdx.x * 256 + threadIdx.x;
    if (i < n4) {
        float4 v = reinterpret_cast<const float4*>(src)[i];
        ushort4v o;
        o.x = f2bf(v.x); o.y = f2bf(v.y); o.z = f2bf(v.z); o.w = f2bf(v.w);
        reinterpret_cast<ushort4v*>(dst)[i] = o;
    }
}

// ---------------------------------------------------------------------------
// Generic TN GEMM: C[m,n] = sum_k A[m,k] * B[n,k]  (A: MxK row-major bf16,
// B: NxK row-major bf16), fp32 accumulate via mfma_f32_16x16x32_bf16.
// EPI 0: outF fp32 = acc + bias
// EPI 1: outU bf16 = acc + bias                       (f_proj)
// EPI 2: init h0/c0: B/bias select by n<512; tanh; n<512 -> x h-slice bf16,
//        else c_state fp32                            (h0c0)
// EPI 3: logits fp32: acc + bias; zero if lengths[m] <= t; N-edge guarded;
//        out[(m*STEPS + t)*V + n]                     (logits)
// ---------------------------------------------------------------------------
template <int BM, int BN, int BK, int EPI>
__global__ __launch_bounds__(256) void gemm_tn(
    const unsigned short* __restrict__ A, int lda,
    const unsigned short* __restrict__ Bm, int ldb,
    const unsigned short* __restrict__ Bm2,
    const float* __restrict__ bias,
    const float* __restrict__ bias2,
    float* __restrict__ outF,
    unsigned short* __restrict__ outU,
    float* __restrict__ outF2,
    int N, int K,
    const int* __restrict__ lengths, int t)
{
    constexpr int LDT = BK + 8;  // +16B pad: only 2-way LDS bank aliasing (free)
    __shared__ __align__(16) unsigned short smem[(BM + BN) * LDT];
    unsigned short* sA = smem;
    unsigned short* sB = smem + BM * LDT;

    const int tid = threadIdx.x;
    const int wid = tid >> 6, lane = tid & 63;
    const int wm = wid >> 1, wn = wid & 1;          // 2x2 wave grid
    const int m0 = blockIdx.x * BM, n0 = blockIdx.y * BN;
    constexpr int FM = BM / 32, FN = BN / 32;       // 16x16 frags per wave

    floatx4 acc[FM][FN];
    #pragma unroll
    for (int i = 0; i < FM; i++)
        #pragma unroll
        for (int j = 0; j < FN; j++)
            #pragma unroll
            for (int r = 0; r < 4; r++) acc[i][j][r] = 0.f;

    const int lm = lane & 15, half = lane >> 4;

    for (int k0 = 0; k0 < K; k0 += BK) {
        // stage A tile
        constexpr int ACH = BM * (BK / 8) / 256;
        #pragma unroll
        for (int ii = 0; ii < ACH; ii++) {
            int i = tid + ii * 256;
            int row = i / (BK / 8), ck = i % (BK / 8);
            ushort8 v = *reinterpret_cast<const ushort8*>(
                A + (size_t)(m0 + row) * lda + k0 + ck * 8);
            *reinterpret_cast<ushort8*>(sA + row * LDT + ck * 8) = v;
        }
        // stage B tile (N-edge guard for EPI3, B-select for EPI2)
        constexpr int BCH = BN * (BK / 8) / 256;
        #pragma unroll
        for (int ii = 0; ii < BCH; ii++) {
            int i = tid + ii * 256;
            int row = i / (BK / 8), ck = i % (BK / 8);
            int gn = n0 + row;
            ushort8 v;
            if constexpr (EPI == 2) {
                const unsigned short* src = (gn < Hc) ? (Bm + (size_t)gn * ldb)
                                                      : (Bm2 + (size_t)(gn - Hc) * ldb);
                v = *reinterpret_cast<const ushort8*>(src + k0 + ck * 8);
            } else if constexpr (EPI == 3) {
                if (gn < N) {
                    v = *reinterpret_cast<const ushort8*>(Bm + (size_t)gn * ldb + k0 + ck * 8);
                } else {
                    #pragma unroll
                    for (int j = 0; j < 8; j++) v[j] = 0;
                }
            } else {
                v = *reinterpret_cast<const ushort8*>(Bm + (size_t)gn * ldb + k0 + ck * 8);
            }
            *reinterpret_cast<ushort8*>(sB + row * LDT + ck * 8) = v;
        }
        __syncthreads();

        #pragma unroll
        for (int kk = 0; kk < BK; kk += 32) {
            bf16x8 af[FM], bfb[FN];
            #pragma unroll
            for (int fm = 0; fm < FM; fm++)
                af[fm] = *reinterpret_cast<const bf16x8*>(
                    sA + (wm * (BM / 2) + fm * 16 + lm) * LDT + kk + half * 8);
            #pragma unroll
            for (int fn = 0; fn < FN; fn++)
                bfb[fn] = *reinterpret_cast<const bf16x8*>(
                    sB + (wn * (BN / 2) + fn * 16 + lm) * LDT + kk + half * 8);
            #pragma unroll
            for (int fm = 0; fm < FM; fm++)
                #pragma unroll
                for (int fn = 0; fn < FN; fn++)
                    acc[fm][fn] = __builtin_amdgcn_mfma_f32_16x16x32_bf16(
                        af[fm], bfb[fn], acc[fm][fn], 0, 0, 0);
        }
        __syncthreads();
    }

    // epilogue: C/D layout col=lane&15, row=(lane>>4)*4+reg  [m89-verified]
    const int quad = lane >> 4;
    #pragma unroll
    for (int fm = 0; fm < FM; fm++) {
        #pragma unroll
        for (int fn = 0; fn < FN; fn++) {
            #pragma unroll
            for (int r = 0; r < 4; r++) {
                int rowG = m0 + wm * (BM / 2) + fm * 16 + quad * 4 + r;
                int colG = n0 + wn * (BN / 2) + fn * 16 + lm;
                float v = acc[fm][fn][r];
                if constexpr (EPI == 0) {
                    outF[(size_t)rowG * N + colG] = v + bias[colG];
                } else if constexpr (EPI == 1) {
                    outU[(size_t)rowG * N + colG] = f2bf(v + bias[colG]);
                } else if constexpr (EPI == 2) {
                    float b = (colG < Hc) ? bias[colG] : bias2[colG - Hc];
                    v = tanhf(v + b);
                    if (colG < Hc) outU[(size_t)rowG * XK + (Ec + Fc) + colG] = f2bf(v);
                    else           outF2[(size_t)rowG * Hc + (colG - Hc)] = v;
                } else {  // EPI == 3
                    if (colG < N) {
                        v += bias[colG];
                        if (lengths[rowG] <= t) v = 0.f;
                        outF[((size_t)rowG * STEPS + t) * Vc + colG] = v;
                    }
                }
            }
        }
    }
}

// ---------------------------------------------------------------------------
// Fused attention: per block b: scores[r] = Ws . tanh(fproj[b,r,:] + hp[b,:])
// + bs ; softmax over R ; ctx = sum_r alpha[r] * featsB[b,r,:] -> x ctx slice.
// ---------------------------------------------------------------------------
__global__ __launch_bounds__(256) void attn_kernel(
    const unsigned short* __restrict__ fproj,
    const float* __restrict__ hp,
    const unsigned short* __restrict__ featsB,
    const float* __restrict__ Ws,
    const float* __restrict__ bs,
    unsigned short* __restrict__ x)
{
    const int b = blockIdx.x, tid = threadIdx.x;
    const int wid = tid >> 6, lane = tid & 63;
    __shared__ float s_sc[64];

    // per-lane slice of Ws and hp (k = lane*8 .. lane*8+7), reused for all r
    float ws8[8], hp8[8];
    {
        const float* wsb = Ws + lane * 8;
        const float* hpb = hp + (size_t)b * Acn + lane * 8;
        #pragma unroll
        for (int j = 0; j < 8; j++) { ws8[j] = wsb[j]; hp8[j] = hpb[j]; }
    }

    for (int r = wid; r < Rc; r += 4) {
        ushort8 e = *reinterpret_cast<const ushort8*>(
            fproj + ((size_t)b * Rc + r) * Acn + lane * 8);
        float sum = 0.f;
        #pragma unroll
        for (int j = 0; j < 8; j++)
            sum += ws8[j] * tanhf(bf2f(e[j]) + hp8[j]);
        #pragma unroll
        for (int off = 32; off > 0; off >>= 1) sum += __shfl_down(sum, off);
        if (lane == 0) s_sc[r] = sum + bs[0];
    }
    __syncthreads();

    if (wid == 0) {
        float v = (lane < Rc) ? s_sc[lane] : -3.0e38f;
        float mx = v;
        #pragma unroll
        for (int off = 32; off > 0; off >>= 1) mx = fmaxf(mx, __shfl_xor(mx, off));
        float e = (lane < Rc) ? __expf(v - mx) : 0.f;
        float sm = e;
        #pragma unroll
        for (int off = 32; off > 0; off >>= 1) sm += __shfl_xor(sm, off);
        if (lane < Rc) s_sc[lane] = e / sm;
    }
    __syncthreads();

    const int f0 = tid * 8;  // 256 threads * 8 = 2048 = F
    float c[8];
    #pragma unroll
    for (int j = 0; j < 8; j++) c[j] = 0.f;
    for (int r = 0; r < Rc; r++) {
        float a = s_sc[r];
        ushort8 v = *reinterpret_cast<const ushort8*>(
            featsB + ((size_t)(b * Rc + r)) * Fc + f0);
        #pragma unroll
        for (int j = 0; j < 8; j++) c[j] += a * bf2f(v[j]);
    }
    ushort8 o;
    #pragma unroll
    for (int j = 0; j < 8; j++) o[j] = f2bf(c[j]);
    *reinterpret_cast<ushort8*>(x + (size_t)b * XK + Ec + f0) = o;
}

// ---------------------------------------------------------------------------
// Pointwise LSTM cell + ragged mask + next-step embedding gather into x.
// ---------------------------------------------------------------------------
__global__ __launch_bounds__(256) void lstm_pointwise(
    const float* __restrict__ gates,
    float* __restrict__ c_state,
    unsigned short* __restrict__ x,
    const int* __restrict__ lengths,
    const int* __restrict__ ids,
    const unsigned short* __restrict__ embB,
    int t)
{
    const int b = blockIdx.x, tid = threadIdx.x;
    const bool active = lengths[b] > t;
    const float* g = gates + (size_t)b * 2048;
    #pragma unroll
    for (int jj = 0; jj < 2; jj++) {
        int j = tid + jj * 256;
        float gi = g[j], gf = g[512 + j], gg = g[1024 + j], go = g[1536 + j];
        float i_ = 1.f / (1.f + __expf(-gi));
        float f_ = 1.f / (1.f + __expf(-gf));
        float gv = tanhf(gg);
        float o_ = 1.f / (1.f + __expf(-go));
        float c  = c_state[(size_t)b * Hc + j];
        float ct = f_ * c + i_ * gv;
        float ht = o_ * tanhf(ct);
        if (active) {
            c_state[(size_t)b * Hc + j] = ct;
            x[(size_t)b * XK + (Ec + Fc) + j] = f2bf(ht);
        }
    }
    if (t + 1 < STEPS && tid < Ec) {
        int id = ids[b * Lc + (t + 1)];
        x[(size_t)b * XK + tid] = embB[(size_t)id * Ec + tid];
    }
}

// ---------------------------------------------------------------------------
// Setup: pack W' = [W_ih | W_hh] (2048 x 2816) converting fp32->bf16,
// bias_g = b_ih + b_hh (fp32).
// ---------------------------------------------------------------------------
__global__ __launch_bounds__(256) void pack_kernel(
    const float* __restrict__ W_ih,
    const float* __restrict__ W_hh,
    const float* __restrict__ b_ih,
    const float* __restrict__ b_hh,
    unsigned short* __restrict__ Wp,
    float* __restrict__ bias_g)
{
    const int n = blockIdx.x, tid = threadIdx.x;
    for (int i = tid; i < (Ec + Fc) / 4; i += 256) {
        float4 v = reinterpret_cast<const float4*>(W_ih + (size_t)n * (Ec + Fc))[i];
        ushort4v o; o.x = f2bf(v.x); o.y = f2bf(v.y); o.z = f2bf(v.z); o.w = f2bf(v.w);
        reinterpret_cast<ushort4v*>(Wp + (size_t)n * XK)[i] = o;
    }
    for (int i = tid; i < Hc / 4; i += 256) {
        float4 v = reinterpret_cast<const float4*>(W_hh + (size_t)n * Hc)[i];
        ushort4v o; o.x = f2bf(v.x); o.y = f2bf(v.y); o.z = f2bf(v.z); o.w = f2bf(v.w);
        reinterpret_cast<ushort4v*>(Wp + (size_t)n * XK + (Ec + Fc))[i] = o;
    }
    if (tid == 0) bias_g[n] = b_ih[n] + b_hh[n];
}

// ---------------------------------------------------------------------------
// Setup: mean over R of featsB (bf16 out, GEMM A-operand) + emb[:,0] gather.
// ---------------------------------------------------------------------------
__global__ __launch_bounds__(256) void mean_emb_kernel(
    const unsigned short* __restrict__ featsB,
    const int* __restrict__ ids,
    const unsigned short* __restrict__ embB,
    unsigned short* __restrict__ meanB,
    unsigned short* __restrict__ x)
{
    const int b = blockIdx.x, tid = threadIdx.x;
    const int f0 = tid * 8;
    float s[8];
    #pragma unroll
    for (int j = 0; j < 8; j++) s[j] = 0.f;
    for (int r = 0; r < Rc; r++) {
        ushort8 v = *reinterpret_cast<const ushort8*>(
            featsB + ((size_t)(b * Rc + r)) * Fc + f0);
        #pragma unroll
        for (int j = 0; j < 8; j++) s[j] += bf2f(v[j]);
    }
    ushort8 o;
    #pragma unroll
    for (int j = 0; j < 8; j++) o[j] = f2bf(s[j] * (1.f / (float)Rc));
    *reinterpret_cast<ushort8*>(meanB + (size_t)b * Fc + f0) = o;
    if (tid < Ec) {
        int id = ids[b * Lc + 0];
        x[(size_t)b * XK + tid] = embB[(size_t)id * Ec + tid];
    }
}

// ---------------------------------------------------------------------------
extern "C" void kernel_launch(void* const* d_in, const int* in_sizes, int n_in,
                              void* d_out, int out_size, void* d_ws, size_t ws_size,
                              hipStream_t stream)
{
    const float* feats = (const float*)d_in[0];
    const int*   ids   = (const int*)d_in[1];
    const int*   lens  = (const int*)d_in[2];
    const float* embW  = (const float*)d_in[3];
    const float* Wf    = (const float*)d_in[4];
    const float* bf_   = (const float*)d_in[5];
    const float* Wh    = (const float*)d_in[6];
    const float* bh    = (const float*)d_in[7];
    const float* Ws_   = (const float*)d_in[8];
    const float* bs_   = (const float*)d_in[9];
    const float* W_ih  = (const float*)d_in[10];
    const float* b_ih  = (const float*)d_in[11];
    const float* W_hh  = (const float*)d_in[12];
    const float* b_hh  = (const float*)d_in[13];
    const float* Wfc   = (const float*)d_in[14];
    const float* bfc   = (const float*)d_in[15];
    const float* Wi_h  = (const float*)d_in[16];
    const float* bi_h  = (const float*)d_in[17];
    const float* Wi_c  = (const float*)d_in[18];
    const float* bi_c  = (const float*)d_in[19];

    char* ws = (char*)d_ws;
    auto alloc_us = [&](size_t n) { unsigned short* p = (unsigned short*)ws; ws += n * 2; return p; };
    auto alloc_f  = [&](size_t n) { float* p = (float*)ws; ws += n * 4; return p; };

    unsigned short* Wp     = alloc_us((size_t)2048 * XK);
    float*          bias_g = alloc_f(2048);
    unsigned short* featsB = alloc_us((size_t)Bc * Rc * Fc);
    unsigned short* embB   = alloc_us((size_t)Vc * Ec);
    unsigned short* WfB    = alloc_us((size_t)Acn * Fc);
    unsigned short* WhB    = alloc_us((size_t)Acn * Hc);
    unsigned short* WfcB   = alloc_us((size_t)Vc * Hc);
    unsigned short* WihB   = alloc_us((size_t)Hc * Fc);
    unsigned short* WicB   = alloc_us((size_t)Hc * Fc);
    unsigned short* meanB  = alloc_us((size_t)Bc * Fc);
    unsigned short* fproj  = alloc_us((size_t)Bc * Rc * Acn);
    unsigned short* x      = alloc_us((size_t)Bc * XK);
    float*          c_st   = alloc_f((size_t)Bc * Hc);
    float*          hp     = alloc_f((size_t)Bc * Hc);
    float*          gates  = alloc_f((size_t)Bc * 2048);
    float*          outF   = (float*)d_out;

    auto cvt = [&](const float* s, unsigned short* d, size_t n) {
        int n4 = (int)(n / 4);
        convert_f2b<<<(n4 + 255) / 256, 256, 0, stream>>>(s, d, n4);
    };
    cvt(feats, featsB, (size_t)Bc * Rc * Fc);
    cvt(embW,  embB,   (size_t)Vc * Ec);
    cvt(Wf,    WfB,    (size_t)Acn * Fc);
    cvt(Wh,    WhB,    (size_t)Acn * Hc);
    cvt(Wfc,   WfcB,   (size_t)Vc * Hc);
    cvt(Wi_h,  WihB,   (size_t)Hc * Fc);
    cvt(Wi_c,  WicB,   (size_t)Hc * Fc);

    pack_kernel<<<2048, 256, 0, stream>>>(W_ih, W_hh, b_ih, b_hh, Wp, bias_g);
    mean_emb_kernel<<<Bc, 256, 0, stream>>>(featsB, ids, embB, meanB, x);

    // h0/c0 init: M=256, N=1024 (Wi_h|Wi_c), K=2048, tanh epilogue
    gemm_tn<64, 64, 64, 2><<<dim3(4, 16), 256, 0, stream>>>(
        meanB, Fc, WihB, Fc, WicB, bi_h, bi_c,
        nullptr, x, c_st, 2 * Hc, Fc, nullptr, 0);

    // f_proj: M=12544, N=512, K=2048 -> bf16
    gemm_tn<128, 128, 64, 1><<<dim3(98, 4), 256, 0, stream>>>(
        featsB, Fc, WfB, Fc, nullptr, bf_, nullptr,
        nullptr, fproj, nullptr, Acn, Fc, nullptr, 0);

    for (int t = 0; t < STEPS; t++) {
        // hp = h @ Wh^T + bh : M=256, N=512, K=512 -> fp32
        gemm_tn<64, 64, 64, 0><<<dim3(4, 8), 256, 0, stream>>>(
            x + (Ec + Fc), XK, WhB, Hc, nullptr, bh, nullptr,
            hp, nullptr, nullptr, Hc, Hc, nullptr, 0);

        attn_kernel<<<Bc, 256, 0, stream>>>(fproj, hp, featsB, Ws_, bs_, x);

        // gates = [emb|ctx|h] @ [W_ih|W_hh]^T + b : M=256, N=2048, K=2816
        gemm_tn<64, 64, 64, 0><<<dim3(4, 32), 256, 0, stream>>>(
            x, XK, Wp, XK, nullptr, bias_g, nullptr,
            gates, nullptr, nullptr, 2048, XK, nullptr, 0);

        lstm_pointwise<<<Bc, 256, 0, stream>>>(gates, c_st, x, lens, ids, embB, t);

        // logits = h_t @ Wfc^T + bfc, ragged-masked: M=256, N=10000, K=512
        gemm_tn<64, 64, 64, 3><<<dim3(4, 157), 256, 0, stream>>>(
            x + (Ec + Fc), XK, WfcB, Hc, nullptr, bfc, nullptr,
            outF, nullptr, nullptr, Vc, Hc, lens, t);
    }
}

// Round 3
// 3295.575 us; speedup vs baseline: 1.0145x; 1.0145x over previous
//
#include <hip/hip_runtime.h>

// Problem constants (DecoderLSTMAttn): B=256, L=24, R=49, F=2048, E=256, H=512, A=512, V=10000
constexpr int Bc = 256, Lc = 24, Rc = 49, Fc = 2048, Ec = 256, Hc = 512, Acn = 512, Vc = 10000;
constexpr int STEPS = Lc - 1;           // 23
constexpr int XK = Ec + Fc + Hc;        // 2816: x = [emb | ctx | h]

using bf16x8  = __attribute__((ext_vector_type(8))) __bf16;
using floatx4 = __attribute__((ext_vector_type(4))) float;
using ushort8 = __attribute__((ext_vector_type(8))) unsigned short;
using ushort4v = __attribute__((ext_vector_type(4))) unsigned short;

__device__ inline float bf2f(unsigned short u) {
    unsigned int x = ((unsigned int)u) << 16;
    float f; __builtin_memcpy(&f, &x, sizeof(f)); return f;
}
__device__ inline unsigned short f2bf(float f) {
    unsigned int u; __builtin_memcpy(&u, &f, sizeof(u));
    u += 0x7fffu + ((u >> 16) & 1u);
    return (unsigned short)(u >> 16);
}

// ---------------------------------------------------------------------------
// fp32 -> bf16 bulk convert (n multiple of 4)
// ---------------------------------------------------------------------------
__global__ __launch_bounds__(256) void convert_f2b(
    const float* __restrict__ src, unsigned short* __restrict__ dst, int n4)
{
    int i = blockIdx.x * 256 + threadIdx.x;
    if (i < n4) {
        float4 v = reinterpret_cast<const float4*>(src)[i];
        ushort4v o;
        o.x = f2bf(v.x); o.y = f2bf(v.y); o.z = f2bf(v.z); o.w = f2bf(v.w);
        reinterpret_cast<ushort4v*>(dst)[i] = o;
    }
}

// ---------------------------------------------------------------------------
// Generic TN GEMM: C[m,n] = sum_k A[m,k]*B[n,k], bf16 in, fp32 acc, MFMA.
// blockIdx.z = split-K slice: A,Bm advance z*K in k; outF advances z*partStride.
// EPI 0: outF fp32 = acc (+bias if non-null)           (gates partials)
// EPI 1: outU bf16 = acc + bias                        (f_proj)
// EPI 2: h0/c0: B/bias select by n<512; tanh; n<512 -> x h-slice bf16,
//        else c_state fp32                             (h0c0)
// EPI 4: batched logits fp32: rowG=(t*256+b); acc+bias; zero if lengths[b]<=t;
//        out[(b*STEPS+t)*V + n]; N-edge guarded        (logits, end of launch)
// ---------------------------------------------------------------------------
template <int BM, int BN, int BK, int EPI>
__global__ __launch_bounds__(256) void gemm_tn(
    const unsigned short* __restrict__ A, int lda,
    const unsigned short* __restrict__ Bm, int ldb,
    const unsigned short* __restrict__ Bm2,
    const float* __restrict__ bias,
    const float* __restrict__ bias2,
    float* __restrict__ outF,
    unsigned short* __restrict__ outU,
    float* __restrict__ outF2,
    int N, int K, size_t partStride,
    const int* __restrict__ lengths)
{
    constexpr int LDT = BK + 8;  // +16B pad: only 2-way LDS bank aliasing (free)
    __shared__ __align__(16) unsigned short smem[(BM + BN) * LDT];
    unsigned short* sA = smem;
    unsigned short* sB = smem + BM * LDT;

    A    += (size_t)blockIdx.z * K;      // split-K slice offset (k-direction)
    Bm   += (size_t)blockIdx.z * K;
    outF += (size_t)blockIdx.z * partStride;

    const int tid = threadIdx.x;
    const int wid = tid >> 6, lane = tid & 63;
    const int wm = wid >> 1, wn = wid & 1;          // 2x2 wave grid
    const int m0 = blockIdx.x * BM, n0 = blockIdx.y * BN;
    constexpr int FM = BM / 32, FN = (BN + 31) / 32;

    floatx4 acc[FM][FN];
    #pragma unroll
    for (int i = 0; i < FM; i++)
        #pragma unroll
        for (int j = 0; j < FN; j++)
            #pragma unroll
            for (int r = 0; r < 4; r++) acc[i][j][r] = 0.f;

    const int lm = lane & 15, half = lane >> 4;

    for (int k0 = 0; k0 < K; k0 += BK) {
        constexpr int ACH = BM * (BK / 8) / 256;
        #pragma unroll
        for (int ii = 0; ii < ACH; ii++) {
            int i = tid + ii * 256;
            int row = i / (BK / 8), ck = i % (BK / 8);
            ushort8 v = *reinterpret_cast<const ushort8*>(
                A + (size_t)(m0 + row) * lda + k0 + ck * 8);
            *reinterpret_cast<ushort8*>(sA + row * LDT + ck * 8) = v;
        }
        constexpr int BCH = BN * (BK / 8) / 256;
        #pragma unroll
        for (int ii = 0; ii < (BCH > 0 ? BCH : 1); ii++) {
            int i = tid + ii * 256;
            if (BCH == 0 && i >= BN * (BK / 8)) break;
            int row = i / (BK / 8), ck = i % (BK / 8);
            int gn = n0 + row;
            ushort8 v;
            if constexpr (EPI == 2) {
                const unsigned short* src = (gn < Hc) ? (Bm + (size_t)gn * ldb)
                                                      : (Bm2 + (size_t)(gn - Hc) * ldb);
                v = *reinterpret_cast<const ushort8*>(src + k0 + ck * 8);
            } else if constexpr (EPI == 4) {
                if (gn < N) {
                    v = *reinterpret_cast<const ushort8*>(Bm + (size_t)gn * ldb + k0 + ck * 8);
                } else {
                    #pragma unroll
                    for (int j = 0; j < 8; j++) v[j] = 0;
                }
            } else {
                v = *reinterpret_cast<const ushort8*>(Bm + (size_t)gn * ldb + k0 + ck * 8);
            }
            *reinterpret_cast<ushort8*>(sB + row * LDT + ck * 8) = v;
        }
        __syncthreads();

        #pragma unroll
        for (int kk = 0; kk < BK; kk += 32) {
            bf16x8 af[FM], bfb[FN];
            #pragma unroll
            for (int fm = 0; fm < FM; fm++)
                af[fm] = *reinterpret_cast<const bf16x8*>(
                    sA + (wm * (BM / 2) + fm * 16 + lm) * LDT + kk + half * 8);
            #pragma unroll
            for (int fn = 0; fn < FN; fn++)
                bfb[fn] = *reinterpret_cast<const bf16x8*>(
                    sB + (wn * (BN / 2) + fn * 16 + lm) * LDT + kk + half * 8);
            #pragma unroll
            for (int fm = 0; fm < FM; fm++)
                #pragma unroll
                for (int fn = 0; fn < FN; fn++)
                    acc[fm][fn] = __builtin_amdgcn_mfma_f32_16x16x32_bf16(
                        af[fm], bfb[fn], acc[fm][fn], 0, 0, 0);
        }
        __syncthreads();
    }

    // epilogue: C/D layout col=lane&15, row=(lane>>4)*4+reg  [m89-verified]
    const int quad = lane >> 4;
    #pragma unroll
    for (int fm = 0; fm < FM; fm++) {
        #pragma unroll
        for (int fn = 0; fn < FN; fn++) {
            #pragma unroll
            for (int r = 0; r < 4; r++) {
                int rowG = m0 + wm * (BM / 2) + fm * 16 + quad * 4 + r;
                int colG = n0 + wn * (BN / 2) + fn * 16 + lm;
                float v = acc[fm][fn][r];
                if constexpr (EPI == 0) {
                    if (bias) v += bias[colG];
                    outF[(size_t)rowG * N + colG] = v;
                } else if constexpr (EPI == 1) {
                    outU[(size_t)rowG * N + colG] = f2bf(v + bias[colG]);
                } else if constexpr (EPI == 2) {
                    float b = (colG < Hc) ? bias[colG] : bias2[colG - Hc];
                    v = tanhf(v + b);
                    if (colG < Hc) outU[(size_t)rowG * XK + (Ec + Fc) + colG] = f2bf(v);
                    else           outF2[(size_t)rowG * Hc + (colG - Hc)] = v;
                } else {  // EPI == 4: batched logits
                    if (colG < N) {
                        int tt = rowG >> 8;        // rowG = t*256 + b
                        int bb = rowG & 255;
                        v += bias[colG];
                        if (lengths[bb] <= tt) v = 0.f;
                        outF[((size_t)bb * STEPS + tt) * Vc + colG] = v;
                    }
                }
            }
        }
    }
}

// ---------------------------------------------------------------------------
// Fused per-step attention, hp computed in-block:
//   hp[n] = bh[n] + sum_k h[b,k]*Wh[n,k]   (4 waves x 128 rows, butterfly)
//   scores[r] = Ws . tanh(fproj[b,r,:] + hp) + bs ; softmax ; ctx -> x ctx slice
// ---------------------------------------------------------------------------
__global__ __launch_bounds__(256) void attn_kernel(
    const unsigned short* __restrict__ fproj,
    const unsigned short* __restrict__ featsB,
    const unsigned short* __restrict__ WhB,
    const float* __restrict__ bh,
    const float* __restrict__ Ws,
    const float* __restrict__ bs,
    unsigned short* __restrict__ x)
{
    const int b = blockIdx.x, tid = threadIdx.x;
    const int wid = tid >> 6, lane = tid & 63;
    __shared__ float s_hp[Acn];
    __shared__ float s_sc[64];

    // per-lane slice of h (k = lane*8 .. +7), bf16 -> fp32
    float h8[8];
    {
        ushort8 hv = *reinterpret_cast<const ushort8*>(
            x + (size_t)b * XK + (Ec + Fc) + lane * 8);
        #pragma unroll
        for (int j = 0; j < 8; j++) h8[j] = bf2f(hv[j]);
    }

    // hp phase: wave w computes rows [w*128, w*128+128)
    for (int n = wid * 128; n < wid * 128 + 128; n++) {
        ushort8 wv = *reinterpret_cast<const ushort8*>(WhB + (size_t)n * Hc + lane * 8);
        float s = 0.f;
        #pragma unroll
        for (int j = 0; j < 8; j++) s += h8[j] * bf2f(wv[j]);
        #pragma unroll
        for (int off = 32; off > 0; off >>= 1) s += __shfl_xor(s, off);
        if (lane == 0) s_hp[n] = s + bh[n];
    }
    __syncthreads();

    // score phase
    float ws8[8], hp8[8];
    {
        const float* wsb = Ws + lane * 8;
        #pragma unroll
        for (int j = 0; j < 8; j++) { ws8[j] = wsb[j]; hp8[j] = s_hp[lane * 8 + j]; }
    }
    for (int r = wid; r < Rc; r += 4) {
        ushort8 e = *reinterpret_cast<const ushort8*>(
            fproj + ((size_t)b * Rc + r) * Acn + lane * 8);
        float sum = 0.f;
        #pragma unroll
        for (int j = 0; j < 8; j++)
            sum += ws8[j] * tanhf(bf2f(e[j]) + hp8[j]);
        #pragma unroll
        for (int off = 32; off > 0; off >>= 1) sum += __shfl_down(sum, off);
        if (lane == 0) s_sc[r] = sum + bs[0];
    }
    __syncthreads();

    if (wid == 0) {
        float v = (lane < Rc) ? s_sc[lane] : -3.0e38f;
        float mx = v;
        #pragma unroll
        for (int off = 32; off > 0; off >>= 1) mx = fmaxf(mx, __shfl_xor(mx, off));
        float e = (lane < Rc) ? __expf(v - mx) : 0.f;
        float sm = e;
        #pragma unroll
        for (int off = 32; off > 0; off >>= 1) sm += __shfl_xor(sm, off);
        if (lane < Rc) s_sc[lane] = e / sm;
    }
    __syncthreads();

    // ctx phase
    const int f0 = tid * 8;  // 256 threads * 8 = 2048 = F
    float c[8];
    #pragma unroll
    for (int j = 0; j < 8; j++) c[j] = 0.f;
    for (int r = 0; r < Rc; r++) {
        float a = s_sc[r];
        ushort8 v = *reinterpret_cast<const ushort8*>(
            featsB + ((size_t)(b * Rc + r)) * Fc + f0);
        #pragma unroll
        for (int j = 0; j < 8; j++) c[j] += a * bf2f(v[j]);
    }
    ushort8 o;
    #pragma unroll
    for (int j = 0; j < 8; j++) o[j] = f2bf(c[j]);
    *reinterpret_cast<ushort8*>(x + (size_t)b * XK + Ec + f0) = o;
}

// ---------------------------------------------------------------------------
// Pointwise LSTM cell: sums split-K gate partials + bias, updates state,
// records h_all[t], gathers next-step embedding.
// ---------------------------------------------------------------------------
__global__ __launch_bounds__(256) void lstm_pointwise(
    const float* __restrict__ gparts,   // [2][256][2048]
    const float* __restrict__ bias_g,
    float* __restrict__ c_state,
    unsigned short* __restrict__ x,
    unsigned short* __restrict__ h_all, // [STEPS][256][512] bf16
    const int* __restrict__ lengths,
    const int* __restrict__ ids,
    const unsigned short* __restrict__ embB,
    int t)
{
    const int b = blockIdx.x, tid = threadIdx.x;
    const bool active = lengths[b] > t;
    const float* g0 = gparts + (size_t)b * 2048;
    const float* g1 = gparts + (size_t)(Bc + b) * 2048;
    #pragma unroll
    for (int jj = 0; jj < 2; jj++) {
        int j = tid + jj * 256;
        float gi = g0[j]        + g1[j]        + bias_g[j];
        float gf = g0[512 + j]  + g1[512 + j]  + bias_g[512 + j];
        float gg = g0[1024 + j] + g1[1024 + j] + bias_g[1024 + j];
        float go = g0[1536 + j] + g1[1536 + j] + bias_g[1536 + j];
        float i_ = 1.f / (1.f + __expf(-gi));
        float f_ = 1.f / (1.f + __expf(-gf));
        float gv = tanhf(gg);
        float o_ = 1.f / (1.f + __expf(-go));
        float c  = c_state[(size_t)b * Hc + j];
        float ct = f_ * c + i_ * gv;
        float ht = o_ * tanhf(ct);
        unsigned short hb = f2bf(ht);
        h_all[((size_t)t * Bc + b) * Hc + j] = hb;   // logits mask applied later
        if (active) {
            c_state[(size_t)b * Hc + j] = ct;
            x[(size_t)b * XK + (Ec + Fc) + j] = hb;
        }
    }
    if (t + 1 < STEPS && tid < Ec) {
        int id = ids[b * Lc + (t + 1)];
        x[(size_t)b * XK + tid] = embB[(size_t)id * Ec + tid];
    }
}

// ---------------------------------------------------------------------------
// Setup: pack W' = [W_ih | W_hh] (2048 x 2816) fp32->bf16, bias_g = b_ih+b_hh.
// ---------------------------------------------------------------------------
__global__ __launch_bounds__(256) void pack_kernel(
    const float* __restrict__ W_ih,
    const float* __restrict__ W_hh,
    const float* __restrict__ b_ih,
    const float* __restrict__ b_hh,
    unsigned short* __restrict__ Wp,
    float* __restrict__ bias_g)
{
    const int n = blockIdx.x, tid = threadIdx.x;
    for (int i = tid; i < (Ec + Fc) / 4; i += 256) {
        float4 v = reinterpret_cast<const float4*>(W_ih + (size_t)n * (Ec + Fc))[i];
        ushort4v o; o.x = f2bf(v.x); o.y = f2bf(v.y); o.z = f2bf(v.z); o.w = f2bf(v.w);
        reinterpret_cast<ushort4v*>(Wp + (size_t)n * XK)[i] = o;
    }
    for (int i = tid; i < Hc / 4; i += 256) {
        float4 v = reinterpret_cast<const float4*>(W_hh + (size_t)n * Hc)[i];
        ushort4v o; o.x = f2bf(v.x); o.y = f2bf(v.y); o.z = f2bf(v.z); o.w = f2bf(v.w);
        reinterpret_cast<ushort4v*>(Wp + (size_t)n * XK + (Ec + Fc))[i] = o;
    }
    if (tid == 0) bias_g[n] = b_ih[n] + b_hh[n];
}

// ---------------------------------------------------------------------------
// Setup: mean over R of featsB (bf16, GEMM A-operand) + emb[:,0] gather.
// ---------------------------------------------------------------------------
__global__ __launch_bounds__(256) void mean_emb_kernel(
    const unsigned short* __restrict__ featsB,
    const int* __restrict__ ids,
    const unsigned short* __restrict__ embB,
    unsigned short* __restrict__ meanB,
    unsigned short* __restrict__ x)
{
    const int b = blockIdx.x, tid = threadIdx.x;
    const int f0 = tid * 8;
    float s[8];
    #pragma unroll
    for (int j = 0; j < 8; j++) s[j] = 0.f;
    for (int r = 0; r < Rc; r++) {
        ushort8 v = *reinterpret_cast<const ushort8*>(
            featsB + ((size_t)(b * Rc + r)) * Fc + f0);
        #pragma unroll
        for (int j = 0; j < 8; j++) s[j] += bf2f(v[j]);
    }
    ushort8 o;
    #pragma unroll
    for (int j = 0; j < 8; j++) o[j] = f2bf(s[j] * (1.f / (float)Rc));
    *reinterpret_cast<ushort8*>(meanB + (size_t)b * Fc + f0) = o;
    if (tid < Ec) {
        int id = ids[b * Lc + 0];
        x[(size_t)b * XK + tid] = embB[(size_t)id * Ec + tid];
    }
}

// ---------------------------------------------------------------------------
extern "C" void kernel_launch(void* const* d_in, const int* in_sizes, int n_in,
                              void* d_out, int out_size, void* d_ws, size_t ws_size,
                              hipStream_t stream)
{
    const float* feats = (const float*)d_in[0];
    const int*   ids   = (const int*)d_in[1];
    const int*   lens  = (const int*)d_in[2];
    const float* embW  = (const float*)d_in[3];
    const float* Wf    = (const float*)d_in[4];
    const float* bf_   = (const float*)d_in[5];
    const float* Wh    = (const float*)d_in[6];
    const float* bh    = (const float*)d_in[7];
    const float* Ws_   = (const float*)d_in[8];
    const float* bs_   = (const float*)d_in[9];
    const float* W_ih  = (const float*)d_in[10];
    const float* b_ih  = (const float*)d_in[11];
    const float* W_hh  = (const float*)d_in[12];
    const float* b_hh  = (const float*)d_in[13];
    const float* Wfc   = (const float*)d_in[14];
    const float* bfc   = (const float*)d_in[15];
    const float* Wi_h  = (const float*)d_in[16];
    const float* bi_h  = (const float*)d_in[17];
    const float* Wi_c  = (const float*)d_in[18];
    const float* bi_c  = (const float*)d_in[19];

    char* ws = (char*)d_ws;
    auto alloc_us = [&](size_t n) { unsigned short* p = (unsigned short*)ws; ws += n * 2; return p; };
    auto alloc_f  = [&](size_t n) { float* p = (float*)ws; ws += n * 4; return p; };

    unsigned short* Wp     = alloc_us((size_t)2048 * XK);
    float*          bias_g = alloc_f(2048);
    unsigned short* featsB = alloc_us((size_t)Bc * Rc * Fc);
    unsigned short* embB   = alloc_us((size_t)Vc * Ec);
    unsigned short* WfB    = alloc_us((size_t)Acn * Fc);
    unsigned short* WhB    = alloc_us((size_t)Acn * Hc);
    unsigned short* WfcB   = alloc_us((size_t)Vc * Hc);
    unsigned short* WihB   = alloc_us((size_t)Hc * Fc);
    unsigned short* WicB   = alloc_us((size_t)Hc * Fc);
    unsigned short* meanB  = alloc_us((size_t)Bc * Fc);
    unsigned short* fproj  = alloc_us((size_t)Bc * Rc * Acn);
    unsigned short* x      = alloc_us((size_t)Bc * XK);
    unsigned short* h_all  = alloc_us((size_t)STEPS * Bc * Hc);
    float*          c_st   = alloc_f((size_t)Bc * Hc);
    float*          gparts = alloc_f((size_t)2 * Bc * 2048);
    float*          outF   = (float*)d_out;

    auto cvt = [&](const float* s, unsigned short* d, size_t n) {
        int n4 = (int)(n / 4);
        convert_f2b<<<(n4 + 255) / 256, 256, 0, stream>>>(s, d, n4);
    };
    cvt(feats, featsB, (size_t)Bc * Rc * Fc);
    cvt(embW,  embB,   (size_t)Vc * Ec);
    cvt(Wf,    WfB,    (size_t)Acn * Fc);
    cvt(Wh,    WhB,    (size_t)Acn * Hc);
    cvt(Wfc,   WfcB,   (size_t)Vc * Hc);
    cvt(Wi_h,  WihB,   (size_t)Hc * Fc);
    cvt(Wi_c,  WicB,   (size_t)Hc * Fc);

    pack_kernel<<<2048, 256, 0, stream>>>(W_ih, W_hh, b_ih, b_hh, Wp, bias_g);
    mean_emb_kernel<<<Bc, 256, 0, stream>>>(featsB, ids, embB, meanB, x);

    // h0/c0 init: M=256, N=1024 (Wi_h|Wi_c), K=2048, tanh epilogue
    gemm_tn<64, 64, 64, 2><<<dim3(4, 16), 256, 0, stream>>>(
        meanB, Fc, WihB, Fc, WicB, bi_h, bi_c,
        nullptr, x, c_st, 2 * Hc, Fc, 0, nullptr);

    // f_proj: M=12544, N=512, K=2048 -> bf16
    gemm_tn<128, 128, 64, 1><<<dim3(98, 4), 256, 0, stream>>>(
        featsB, Fc, WfB, Fc, nullptr, bf_, nullptr,
        nullptr, fproj, nullptr, Acn, Fc, 0, nullptr);

    for (int t = 0; t < STEPS; t++) {
        attn_kernel<<<Bc, 256, 0, stream>>>(fproj, featsB, WhB, bh, Ws_, bs_, x);

        // gates partials: M=256, N=2048, K=2816 split 2x1408, 64x32 tile
        // grid (4, 64, 2) = 512 blocks
        gemm_tn<64, 32, 64, 0><<<dim3(4, 64, 2), 256, 0, stream>>>(
            x, XK, Wp, XK, nullptr, nullptr, nullptr,
            gparts, nullptr, nullptr, 2048, XK / 2, (size_t)Bc * 2048, nullptr);

        lstm_pointwise<<<Bc, 256, 0, stream>>>(
            gparts, bias_g, c_st, x, h_all, lens, ids, embB, t);
    }

    // batched logits: M=5888 (=23*256), N=10000, K=512, 128x128 tile
    gemm_tn<128, 128, 64, 4><<<dim3(46, 79), 256, 0, stream>>>(
        h_all, Hc, WfcB, Hc, nullptr, bfc, nullptr,
        outF, nullptr, nullptr, Vc, Hc, 0, lens);
}

// Round 4
// 2036.795 us; speedup vs baseline: 1.6414x; 1.6180x over previous
//
#include <hip/hip_runtime.h>

// Problem constants (DecoderLSTMAttn): B=256, L=24, R=49, F=2048, E=256, H=512, A=512, V=10000
constexpr int Bc = 256, Lc = 24, Rc = 49, Fc = 2048, Ec = 256, Hc = 512, Acn = 512, Vc = 10000;
constexpr int STEPS = Lc - 1;           // 23
constexpr int XE = Ec + Fc;             // 2304: x = [emb | ctx]
constexpr int NG = 2048 + Acn;          // 2560: hgemm out = [gate-contrib | hp]

using bf16x8  = __attribute__((ext_vector_type(8))) __bf16;
using floatx4 = __attribute__((ext_vector_type(4))) float;
using ushort8 = __attribute__((ext_vector_type(8))) unsigned short;
using ushort4v = __attribute__((ext_vector_type(4))) unsigned short;

__device__ inline float bf2f(unsigned short u) {
    unsigned int x = ((unsigned int)u) << 16;
    float f; __builtin_memcpy(&f, &x, sizeof(f)); return f;
}
__device__ inline unsigned short f2bf(float f) {
    unsigned int u; __builtin_memcpy(&u, &f, sizeof(u));
    u += 0x7fffu + ((u >> 16) & 1u);
    return (unsigned short)(u >> 16);
}

// ---------------------------------------------------------------------------
// One-shot fp32->bf16 convert of all 9 tensors (constexpr segment table).
// Segment sizes in float4 units.
// ---------------------------------------------------------------------------
struct CvtArgs {
    const float* src[9];
    unsigned short* dst[9];
};
constexpr int SEG_END[9] = {
    6422528,   // feats   256*49*2048/4
    7062528,   // embW    +10000*256/4
    7324672,   // Wf      +512*2048/4
    8604672,   // Wfc     +10000*512/4
    9784320,   // W_ih    +2048*2304/4
    10046464,  // W_hh    +2048*512/4   (-> Whg rows 0..2047)
    10112000,  // Wh      +512*512/4    (-> Whg rows 2048..2559)
    10374144,  // Wi_h    +512*2048/4
    10636288   // Wi_c    +512*2048/4
};
constexpr int CVT_BLOCKS = SEG_END[8] / 256;  // exact

__global__ __launch_bounds__(256) void convert_all(CvtArgs a)
{
    int g = blockIdx.x * 256 + threadIdx.x;
    int s = 0, base = 0;
    #pragma unroll
    for (int i = 0; i < 9; i++)
        if (g >= SEG_END[i]) { s = i + 1; }
    if (s >= 9) return;
    base = (s == 0) ? 0 : SEG_END[s - 1];
    const float* sp = a.src[s];
    unsigned short* dp = a.dst[s];
    int off = g - base;
    float4 v = reinterpret_cast<const float4*>(sp)[off];
    ushort4v o;
    o.x = f2bf(v.x); o.y = f2bf(v.y); o.z = f2bf(v.z); o.w = f2bf(v.w);
    reinterpret_cast<ushort4v*>(dp)[off] = o;
}

// ---------------------------------------------------------------------------
// Generic TN GEMM: C[m,n] = sum_k A[m,k]*B[n,k], bf16 in, fp32 acc, MFMA.
// blockIdx.z = split-K slice: A,Bm advance z*K in k; outF advances z*partStride.
// EPI 0: outF fp32 = acc (+bias if non-null)           (hgemm / xgemm partials)
// EPI 1: outU bf16 = acc + bias                        (f_proj)
// EPI 2: h0/c0: B/bias select by n<512; tanh; n<512 -> h_buf bf16,
//        else c_state fp32                             (h0c0)
// EPI 4: batched logits fp32 (n-major grid): rowG=(t*256+b); acc+bias;
//        zero if lengths[b]<=t; out[(b*STEPS+t)*V+n]; N-edge guarded
// ---------------------------------------------------------------------------
template <int BM, int BN, int BK, int EPI>
__global__ __launch_bounds__(256) void gemm_tn(
    const unsigned short* __restrict__ A, int lda,
    const unsigned short* __restrict__ Bm, int ldb,
    const unsigned short* __restrict__ Bm2,
    const float* __restrict__ bias,
    const float* __restrict__ bias2,
    float* __restrict__ outF,
    unsigned short* __restrict__ outU,
    float* __restrict__ outF2,
    int N, int K, size_t partStride,
    const int* __restrict__ lengths)
{
    constexpr int LDT = BK + 8;  // +16B pad: only 2-way LDS bank aliasing (free)
    __shared__ __align__(16) unsigned short smem[(BM + BN) * LDT];
    unsigned short* sA = smem;
    unsigned short* sB = smem + BM * LDT;

    A    += (size_t)blockIdx.z * K;      // split-K slice offset (k-direction)
    Bm   += (size_t)blockIdx.z * K;
    outF += (size_t)blockIdx.z * partStride;

    const int tid = threadIdx.x;
    const int wid = tid >> 6, lane = tid & 63;
    const int wm = wid >> 1, wn = wid & 1;          // 2x2 wave grid
    constexpr bool NMAJOR = (EPI == 4);             // logits: x = n-tile for L2 reuse
    const int m0 = (NMAJOR ? blockIdx.y : blockIdx.x) * BM;
    const int n0 = (NMAJOR ? blockIdx.x : blockIdx.y) * BN;
    constexpr int FM = BM / 32, FN = (BN + 31) / 32;

    floatx4 acc[FM][FN];
    #pragma unroll
    for (int i = 0; i < FM; i++)
        #pragma unroll
        for (int j = 0; j < FN; j++)
            #pragma unroll
            for (int r = 0; r < 4; r++) acc[i][j][r] = 0.f;

    const int lm = lane & 15, half = lane >> 4;

    for (int k0 = 0; k0 < K; k0 += BK) {
        constexpr int ACH = BM * (BK / 8) / 256;
        #pragma unroll
        for (int ii = 0; ii < ACH; ii++) {
            int i = tid + ii * 256;
            int row = i / (BK / 8), ck = i % (BK / 8);
            ushort8 v = *reinterpret_cast<const ushort8*>(
                A + (size_t)(m0 + row) * lda + k0 + ck * 8);
            *reinterpret_cast<ushort8*>(sA + row * LDT + ck * 8) = v;
        }
        constexpr int BCH = BN * (BK / 8) / 256;
        #pragma unroll
        for (int ii = 0; ii < (BCH > 0 ? BCH : 1); ii++) {
            int i = tid + ii * 256;
            if (BCH == 0 && i >= BN * (BK / 8)) break;
            int row = i / (BK / 8), ck = i % (BK / 8);
            int gn = n0 + row;
            ushort8 v;
            if constexpr (EPI == 2) {
                const unsigned short* src = (gn < Hc) ? (Bm + (size_t)gn * ldb)
                                                      : (Bm2 + (size_t)(gn - Hc) * ldb);
                v = *reinterpret_cast<const ushort8*>(src + k0 + ck * 8);
            } else if constexpr (EPI == 4) {
                if (gn < N) {
                    v = *reinterpret_cast<const ushort8*>(Bm + (size_t)gn * ldb + k0 + ck * 8);
                } else {
                    #pragma unroll
                    for (int j = 0; j < 8; j++) v[j] = 0;
                }
            } else {
                v = *reinterpret_cast<const ushort8*>(Bm + (size_t)gn * ldb + k0 + ck * 8);
            }
            *reinterpret_cast<ushort8*>(sB + row * LDT + ck * 8) = v;
        }
        __syncthreads();

        #pragma unroll
        for (int kk = 0; kk < BK; kk += 32) {
            bf16x8 af[FM], bfb[FN];
            #pragma unroll
            for (int fm = 0; fm < FM; fm++)
                af[fm] = *reinterpret_cast<const bf16x8*>(
                    sA + (wm * (BM / 2) + fm * 16 + lm) * LDT + kk + half * 8);
            #pragma unroll
            for (int fn = 0; fn < FN; fn++)
                bfb[fn] = *reinterpret_cast<const bf16x8*>(
                    sB + (wn * (BN / 2) + fn * 16 + lm) * LDT + kk + half * 8);
            #pragma unroll
            for (int fm = 0; fm < FM; fm++)
                #pragma unroll
                for (int fn = 0; fn < FN; fn++)
                    acc[fm][fn] = __builtin_amdgcn_mfma_f32_16x16x32_bf16(
                        af[fm], bfb[fn], acc[fm][fn], 0, 0, 0);
        }
        __syncthreads();
    }

    // epilogue: C/D layout col=lane&15, row=(lane>>4)*4+reg  [m89-verified]
    const int quad = lane >> 4;
    #pragma unroll
    for (int fm = 0; fm < FM; fm++) {
        #pragma unroll
        for (int fn = 0; fn < FN; fn++) {
            #pragma unroll
            for (int r = 0; r < 4; r++) {
                int rowG = m0 + wm * (BM / 2) + fm * 16 + quad * 4 + r;
                int colG = n0 + wn * (BN / 2) + fn * 16 + lm;
                float v = acc[fm][fn][r];
                if constexpr (EPI == 0) {
                    if (bias) v += bias[colG];
                    outF[(size_t)rowG * N + colG] = v;
                } else if constexpr (EPI == 1) {
                    outU[(size_t)rowG * N + colG] = f2bf(v + bias[colG]);
                } else if constexpr (EPI == 2) {
                    float b = (colG < Hc) ? bias[colG] : bias2[colG - Hc];
                    v = tanhf(v + b);
                    if (colG < Hc) outU[(size_t)rowG * Hc + colG] = f2bf(v);
                    else           outF2[(size_t)rowG * Hc + (colG - Hc)] = v;
                } else {  // EPI == 4: batched logits
                    if (colG < N) {
                        int tt = rowG >> 8;        // rowG = t*256 + b
                        int bb = rowG & 255;
                        v += bias[colG];
                        if (lengths[bb] <= tt) v = 0.f;
                        outF[((size_t)bb * STEPS + tt) * Vc + colG] = v;
                    }
                }
            }
        }
    }
}

// ---------------------------------------------------------------------------
// Light attention: hp from hg[b, 2048:2560] (+bh); scores over fproj; softmax;
// ctx = sum_r alpha[r]*featsB[b,r,:] -> x ctx slice.
// ---------------------------------------------------------------------------
__global__ __launch_bounds__(256) void attn_kernel(
    const unsigned short* __restrict__ fproj,
    const unsigned short* __restrict__ featsB,
    const float* __restrict__ hg,       // [256][2560]
    const float* __restrict__ bh,
    const float* __restrict__ Ws,
    const float* __restrict__ bs,
    unsigned short* __restrict__ x)     // [256][2304] = [emb | ctx]
{
    const int b = blockIdx.x, tid = threadIdx.x;
    const int wid = tid >> 6, lane = tid & 63;
    __shared__ float s_hp[Acn];
    __shared__ float s_sc[64];

    // hp = hg[b, 2048:] + bh  (coalesced, 2 floats/thread)
    #pragma unroll
    for (int i = tid; i < Acn; i += 256)
        s_hp[i] = hg[(size_t)b * NG + 2048 + i] + bh[i];
    __syncthreads();

    // score phase: per-lane k-slice of Ws and hp
    float ws8[8], hp8[8];
    {
        const float* wsb = Ws + lane * 8;
        #pragma unroll
        for (int j = 0; j < 8; j++) { ws8[j] = wsb[j]; hp8[j] = s_hp[lane * 8 + j]; }
    }
    for (int r = wid; r < Rc; r += 4) {
        ushort8 e = *reinterpret_cast<const ushort8*>(
            fproj + ((size_t)b * Rc + r) * Acn + lane * 8);
        float sum = 0.f;
        #pragma unroll
        for (int j = 0; j < 8; j++)
            sum += ws8[j] * tanhf(bf2f(e[j]) + hp8[j]);
        #pragma unroll
        for (int off = 32; off > 0; off >>= 1) sum += __shfl_down(sum, off);
        if (lane == 0) s_sc[r] = sum + bs[0];
    }
    __syncthreads();

    if (wid == 0) {
        float v = (lane < Rc) ? s_sc[lane] : -3.0e38f;
        float mx = v;
        #pragma unroll
        for (int off = 32; off > 0; off >>= 1) mx = fmaxf(mx, __shfl_xor(mx, off));
        float e = (lane < Rc) ? __expf(v - mx) : 0.f;
        float sm = e;
        #pragma unroll
        for (int off = 32; off > 0; off >>= 1) sm += __shfl_xor(sm, off);
        if (lane < Rc) s_sc[lane] = e / sm;
    }
    __syncthreads();

    // ctx phase
    const int f0 = tid * 8;  // 256 threads * 8 = 2048 = F
    float c[8];
    #pragma unroll
    for (int j = 0; j < 8; j++) c[j] = 0.f;
    #pragma unroll 7
    for (int r = 0; r < Rc; r++) {
        float a = s_sc[r];
        ushort8 v = *reinterpret_cast<const ushort8*>(
            featsB + ((size_t)(b * Rc + r)) * Fc + f0);
        #pragma unroll
        for (int j = 0; j < 8; j++) c[j] += a * bf2f(v[j]);
    }
    ushort8 o;
    #pragma unroll
    for (int j = 0; j < 8; j++) o[j] = f2bf(c[j]);
    *reinterpret_cast<ushort8*>(x + (size_t)b * XE + Ec + f0) = o;
}

// ---------------------------------------------------------------------------
// Pointwise LSTM: gates = xg0 + xg1 + hg[:2048] + b_ih + b_hh; state update;
// h_buf (next hgemm A), h_all[t] record, next-step embedding gather.
// ---------------------------------------------------------------------------
__global__ __launch_bounds__(256) void lstm_pointwise(
    const float* __restrict__ xg,       // [2][256][2048]
    const float* __restrict__ hg,       // [256][2560]
    const float* __restrict__ b_ih,
    const float* __restrict__ b_hh,
    float* __restrict__ c_state,
    unsigned short* __restrict__ h_buf, // [256][512] bf16
    unsigned short* __restrict__ h_all, // [STEPS][256][512] bf16
    unsigned short* __restrict__ x,     // [256][2304]
    const int* __restrict__ lengths,
    const int* __restrict__ ids,
    const unsigned short* __restrict__ embB,
    int t)
{
    const int b = blockIdx.x, tid = threadIdx.x;
    const bool active = lengths[b] > t;
    const float* x0 = xg + (size_t)b * 2048;
    const float* x1 = xg + (size_t)(Bc + b) * 2048;
    const float* hgb = hg + (size_t)b * NG;
    #pragma unroll
    for (int jj = 0; jj < 2; jj++) {
        int j = tid + jj * 256;
        float gi = x0[j]        + x1[j]        + hgb[j]        + b_ih[j]        + b_hh[j];
        float gf = x0[512 + j]  + x1[512 + j]  + hgb[512 + j]  + b_ih[512 + j]  + b_hh[512 + j];
        float gg = x0[1024 + j] + x1[1024 + j] + hgb[1024 + j] + b_ih[1024 + j] + b_hh[1024 + j];
        float go = x0[1536 + j] + x1[1536 + j] + hgb[1536 + j] + b_ih[1536 + j] + b_hh[1536 + j];
        float i_ = 1.f / (1.f + __expf(-gi));
        float f_ = 1.f / (1.f + __expf(-gf));
        float gv = tanhf(gg);
        float o_ = 1.f / (1.f + __expf(-go));
        float c  = c_state[(size_t)b * Hc + j];
        float ct = f_ * c + i_ * gv;
        float ht = o_ * tanhf(ct);
        unsigned short hb = f2bf(ht);
        h_all[((size_t)t * Bc + b) * Hc + j] = hb;   // logits mask applied later
        if (active) {
            c_state[(size_t)b * Hc + j] = ct;
            h_buf[(size_t)b * Hc + j] = hb;
        }
    }
    if (t + 1 < STEPS && tid < Ec) {
        int id = ids[b * Lc + (t + 1)];
        x[(size_t)b * XE + tid] = embB[(size_t)id * Ec + tid];
    }
}

// ---------------------------------------------------------------------------
// Setup: mean over R of featsB (bf16, GEMM A-operand) + emb[:,0] gather.
// ---------------------------------------------------------------------------
__global__ __launch_bounds__(256) void mean_emb_kernel(
    const unsigned short* __restrict__ featsB,
    const int* __restrict__ ids,
    const unsigned short* __restrict__ embB,
    unsigned short* __restrict__ meanB,
    unsigned short* __restrict__ x)
{
    const int b = blockIdx.x, tid = threadIdx.x;
    const int f0 = tid * 8;
    float s[8];
    #pragma unroll
    for (int j = 0; j < 8; j++) s[j] = 0.f;
    #pragma unroll 7
    for (int r = 0; r < Rc; r++) {
        ushort8 v = *reinterpret_cast<const ushort8*>(
            featsB + ((size_t)(b * Rc + r)) * Fc + f0);
        #pragma unroll
        for (int j = 0; j < 8; j++) s[j] += bf2f(v[j]);
    }
    ushort8 o;
    #pragma unroll
    for (int j = 0; j < 8; j++) o[j] = f2bf(s[j] * (1.f / (float)Rc));
    *reinterpret_cast<ushort8*>(meanB + (size_t)b * Fc + f0) = o;
    if (tid < Ec) {
        int id = ids[b * Lc + 0];
        x[(size_t)b * XE + tid] = embB[(size_t)id * Ec + tid];
    }
}

// ---------------------------------------------------------------------------
extern "C" void kernel_launch(void* const* d_in, const int* in_sizes, int n_in,
                              void* d_out, int out_size, void* d_ws, size_t ws_size,
                              hipStream_t stream)
{
    const float* feats = (const float*)d_in[0];
    const int*   ids   = (const int*)d_in[1];
    const int*   lens  = (const int*)d_in[2];
    const float* embW  = (const float*)d_in[3];
    const float* Wf    = (const float*)d_in[4];
    const float* bf_   = (const float*)d_in[5];
    const float* Wh    = (const float*)d_in[6];
    const float* bh    = (const float*)d_in[7];
    const float* Ws_   = (const float*)d_in[8];
    const float* bs_   = (const float*)d_in[9];
    const float* W_ih  = (const float*)d_in[10];
    const float* b_ih  = (const float*)d_in[11];
    const float* W_hh  = (const float*)d_in[12];
    const float* b_hh  = (const float*)d_in[13];
    const float* Wfc   = (const float*)d_in[14];
    const float* bfc   = (const float*)d_in[15];
    const float* Wi_h  = (const float*)d_in[16];
    const float* bi_h  = (const float*)d_in[17];
    const float* Wi_c  = (const float*)d_in[18];
    const float* bi_c  = (const float*)d_in[19];

    char* ws = (char*)d_ws;
    auto alloc_us = [&](size_t n) { unsigned short* p = (unsigned short*)ws; ws += n * 2; return p; };
    auto alloc_f  = [&](size_t n) { float* p = (float*)ws; ws += n * 4; return p; };

    unsigned short* featsB = alloc_us((size_t)Bc * Rc * Fc);
    unsigned short* embB   = alloc_us((size_t)Vc * Ec);
    unsigned short* WfB    = alloc_us((size_t)Acn * Fc);
    unsigned short* WfcB   = alloc_us((size_t)Vc * Hc);
    unsigned short* WihB   = alloc_us((size_t)2048 * XE);
    unsigned short* Whg    = alloc_us((size_t)NG * Hc);   // [W_hh ; Wh]
    unsigned short* WihB2  = alloc_us((size_t)Hc * Fc);   // Wi_h
    unsigned short* WicB   = alloc_us((size_t)Hc * Fc);   // Wi_c
    unsigned short* meanB  = alloc_us((size_t)Bc * Fc);
    unsigned short* fproj  = alloc_us((size_t)Bc * Rc * Acn);
    unsigned short* x      = alloc_us((size_t)Bc * XE);
    unsigned short* h_buf  = alloc_us((size_t)Bc * Hc);
    unsigned short* h_all  = alloc_us((size_t)STEPS * Bc * Hc);
    float*          c_st   = alloc_f((size_t)Bc * Hc);
    float*          hg     = alloc_f((size_t)Bc * NG);
    float*          xg     = alloc_f((size_t)2 * Bc * 2048);
    float*          outF   = (float*)d_out;

    CvtArgs ca;
    ca.src[0] = feats; ca.dst[0] = featsB;
    ca.src[1] = embW;  ca.dst[1] = embB;
    ca.src[2] = Wf;    ca.dst[2] = WfB;
    ca.src[3] = Wfc;   ca.dst[3] = WfcB;
    ca.src[4] = W_ih;  ca.dst[4] = WihB;
    ca.src[5] = W_hh;  ca.dst[5] = Whg;                       // rows 0..2047
    ca.src[6] = Wh;    ca.dst[6] = Whg + (size_t)2048 * Hc;   // rows 2048..2559
    ca.src[7] = Wi_h;  ca.dst[7] = WihB2;
    ca.src[8] = Wi_c;  ca.dst[8] = WicB;
    convert_all<<<CVT_BLOCKS, 256, 0, stream>>>(ca);

    mean_emb_kernel<<<Bc, 256, 0, stream>>>(featsB, ids, embB, meanB, x);

    // h0/c0 init: M=256, N=1024 (Wi_h|Wi_c), K=2048, tanh epilogue
    gemm_tn<64, 64, 64, 2><<<dim3(4, 16), 256, 0, stream>>>(
        meanB, Fc, WihB2, Fc, WicB, bi_h, bi_c,
        nullptr, h_buf, c_st, 2 * Hc, Fc, 0, nullptr);

    // f_proj: M=12544, N=512, K=2048 -> bf16
    gemm_tn<128, 128, 64, 1><<<dim3(98, 4), 256, 0, stream>>>(
        featsB, Fc, WfB, Fc, nullptr, bf_, nullptr,
        nullptr, fproj, nullptr, Acn, Fc, 0, nullptr);

    for (int t = 0; t < STEPS; t++) {
        // hgemm: hg = h @ [W_hh;Wh]^T : M=256, N=2560, K=512 (no bias)
        gemm_tn<64, 64, 64, 0><<<dim3(4, 40), 256, 0, stream>>>(
            h_buf, Hc, Whg, Hc, nullptr, nullptr, nullptr,
            hg, nullptr, nullptr, NG, Hc, 0, nullptr);

        attn_kernel<<<Bc, 256, 0, stream>>>(fproj, featsB, hg, bh, Ws_, bs_, x);

        // xgemm partials: M=256, N=2048, K=2304 split 2x1152, 64x32 tile
        gemm_tn<64, 32, 64, 0><<<dim3(4, 64, 2), 256, 0, stream>>>(
            x, XE, WihB, XE, nullptr, nullptr, nullptr,
            xg, nullptr, nullptr, 2048, XE / 2, (size_t)Bc * 2048, nullptr);

        lstm_pointwise<<<Bc, 256, 0, stream>>>(
            xg, hg, b_ih, b_hh, c_st, h_buf, h_all, x, lens, ids, embB, t);
    }

    // batched logits: M=5888 (=23*256), N=10000, K=512, 128x128 tile, n-major grid
    gemm_tn<128, 128, 64, 4><<<dim3(79, 46), 256, 0, stream>>>(
        h_all, Hc, WfcB, Hc, nullptr, bfc, nullptr,
        outF, nullptr, nullptr, Vc, Hc, 0, lens);
}

// Round 5
// 2001.282 us; speedup vs baseline: 1.6705x; 1.0177x over previous
//
#include <hip/hip_runtime.h>

// Problem constants (DecoderLSTMAttn): B=256, L=24, R=49, F=2048, E=256, H=512, A=512, V=10000
constexpr int Bc = 256, Lc = 24, Rc = 49, Fc = 2048, Ec = 256, Hc = 512, Acn = 512, Vc = 10000;
constexpr int STEPS = Lc - 1;           // 23
constexpr int XE = Ec + Fc;             // 2304: x = [emb | ctx]
constexpr int NG = 2048 + Acn;          // 2560: hgemm out = [gate-contrib | hp]

using bf16x8  = __attribute__((ext_vector_type(8))) __bf16;
using floatx4 = __attribute__((ext_vector_type(4))) float;
using ushort8 = __attribute__((ext_vector_type(8))) unsigned short;
using ushort4v = __attribute__((ext_vector_type(4))) unsigned short;

__device__ inline float bf2f(unsigned short u) {
    unsigned int x = ((unsigned int)u) << 16;
    float f; __builtin_memcpy(&f, &x, sizeof(f)); return f;
}
__device__ inline unsigned short f2bf(float f) {
    unsigned int u; __builtin_memcpy(&u, &f, sizeof(u));
    u += 0x7fffu + ((u >> 16) & 1u);
    return (unsigned short)(u >> 16);
}

// ---------------------------------------------------------------------------
// One-shot fp32->bf16 convert of all 9 tensors (constexpr segment table).
// ---------------------------------------------------------------------------
struct CvtArgs {
    const float* src[9];
    unsigned short* dst[9];
};
constexpr int SEG_END[9] = {
    6422528,   // feats   256*49*2048/4
    7062528,   // embW    +10000*256/4
    7324672,   // Wf      +512*2048/4
    8604672,   // Wfc     +10000*512/4
    9784320,   // W_ih    +2048*2304/4
    10046464,  // W_hh    +2048*512/4   (-> Whg rows 0..2047)
    10112000,  // Wh      +512*512/4    (-> Whg rows 2048..2559)
    10374144,  // Wi_h    +512*2048/4
    10636288   // Wi_c    +512*2048/4
};
constexpr int CVT_BLOCKS = SEG_END[8] / 256;  // exact

__global__ __launch_bounds__(256) void convert_all(CvtArgs a)
{
    int g = blockIdx.x * 256 + threadIdx.x;
    int s = 0, base = 0;
    #pragma unroll
    for (int i = 0; i < 9; i++)
        if (g >= SEG_END[i]) { s = i + 1; }
    if (s >= 9) return;
    base = (s == 0) ? 0 : SEG_END[s - 1];
    const float* sp = a.src[s];
    unsigned short* dp = a.dst[s];
    int off = g - base;
    float4 v = reinterpret_cast<const float4*>(sp)[off];
    ushort4v o;
    o.x = f2bf(v.x); o.y = f2bf(v.y); o.z = f2bf(v.z); o.w = f2bf(v.w);
    reinterpret_cast<ushort4v*>(dp)[off] = o;
}

// ---------------------------------------------------------------------------
// Generic TN GEMM (bf16 in, fp32 acc, MFMA 16x16x32).
// EPI 0: outF fp32 = acc (+bias if non-null)           (hgemm)
// EPI 1: outU bf16 = acc + bias                        (f_proj)
// EPI 2: h0/c0: B/bias select by n<512; tanh; n<512 -> h_buf bf16,
//        else c_state fp32                             (h0c0)
// ---------------------------------------------------------------------------
template <int BM, int BN, int BK, int EPI>
__global__ __launch_bounds__(256) void gemm_tn(
    const unsigned short* __restrict__ A, int lda,
    const unsigned short* __restrict__ Bm, int ldb,
    const unsigned short* __restrict__ Bm2,
    const float* __restrict__ bias,
    const float* __restrict__ bias2,
    float* __restrict__ outF,
    unsigned short* __restrict__ outU,
    float* __restrict__ outF2,
    int N, int K)
{
    constexpr int LDT = BK + 8;
    __shared__ __align__(16) unsigned short smem[(BM + BN) * LDT];
    unsigned short* sA = smem;
    unsigned short* sB = smem + BM * LDT;

    const int tid = threadIdx.x;
    const int wid = tid >> 6, lane = tid & 63;
    const int wm = wid >> 1, wn = wid & 1;
    const int m0 = blockIdx.x * BM, n0 = blockIdx.y * BN;
    constexpr int FM = BM / 32, FN = (BN + 31) / 32;

    floatx4 acc[FM][FN];
    #pragma unroll
    for (int i = 0; i < FM; i++)
        #pragma unroll
        for (int j = 0; j < FN; j++)
            #pragma unroll
            for (int r = 0; r < 4; r++) acc[i][j][r] = 0.f;

    const int lm = lane & 15, half = lane >> 4;

    for (int k0 = 0; k0 < K; k0 += BK) {
        constexpr int ACH = BM * (BK / 8) / 256;
        #pragma unroll
        for (int ii = 0; ii < ACH; ii++) {
            int i = tid + ii * 256;
            int row = i / (BK / 8), ck = i % (BK / 8);
            ushort8 v = *reinterpret_cast<const ushort8*>(
                A + (size_t)(m0 + row) * lda + k0 + ck * 8);
            *reinterpret_cast<ushort8*>(sA + row * LDT + ck * 8) = v;
        }
        constexpr int BCH = BN * (BK / 8) / 256;
        #pragma unroll
        for (int ii = 0; ii < (BCH > 0 ? BCH : 1); ii++) {
            int i = tid + ii * 256;
            if (BCH == 0 && i >= BN * (BK / 8)) break;
            int row = i / (BK / 8), ck = i % (BK / 8);
            int gn = n0 + row;
            ushort8 v;
            if constexpr (EPI == 2) {
                const unsigned short* src = (gn < Hc) ? (Bm + (size_t)gn * ldb)
                                                      : (Bm2 + (size_t)(gn - Hc) * ldb);
                v = *reinterpret_cast<const ushort8*>(src + k0 + ck * 8);
            } else {
                v = *reinterpret_cast<const ushort8*>(Bm + (size_t)gn * ldb + k0 + ck * 8);
            }
            *reinterpret_cast<ushort8*>(sB + row * LDT + ck * 8) = v;
        }
        __syncthreads();

        #pragma unroll
        for (int kk = 0; kk < BK; kk += 32) {
            bf16x8 af[FM], bfb[FN];
            #pragma unroll
            for (int fm = 0; fm < FM; fm++)
                af[fm] = *reinterpret_cast<const bf16x8*>(
                    sA + (wm * (BM / 2) + fm * 16 + lm) * LDT + kk + half * 8);
            #pragma unroll
            for (int fn = 0; fn < FN; fn++)
                bfb[fn] = *reinterpret_cast<const bf16x8*>(
                    sB + (wn * (BN / 2) + fn * 16 + lm) * LDT + kk + half * 8);
            #pragma unroll
            for (int fm = 0; fm < FM; fm++)
                #pragma unroll
                for (int fn = 0; fn < FN; fn++)
                    acc[fm][fn] = __builtin_amdgcn_mfma_f32_16x16x32_bf16(
                        af[fm], bfb[fn], acc[fm][fn], 0, 0, 0);
        }
        __syncthreads();
    }

    const int quad = lane >> 4;
    #pragma unroll
    for (int fm = 0; fm < FM; fm++) {
        #pragma unroll
        for (int fn = 0; fn < FN; fn++) {
            #pragma unroll
            for (int r = 0; r < 4; r++) {
                int rowG = m0 + wm * (BM / 2) + fm * 16 + quad * 4 + r;
                int colG = n0 + wn * (BN / 2) + fn * 16 + lm;
                float v = acc[fm][fn][r];
                if constexpr (EPI == 0) {
                    if (bias) v += bias[colG];
                    outF[(size_t)rowG * N + colG] = v;
                } else if constexpr (EPI == 1) {
                    outU[(size_t)rowG * N + colG] = f2bf(v + bias[colG]);
                } else if constexpr (EPI == 2) {
                    float b = (colG < Hc) ? bias[colG] : bias2[colG - Hc];
                    v = tanhf(v + b);
                    if (colG < Hc) outU[(size_t)rowG * Hc + colG] = f2bf(v);
                    else           outF2[(size_t)rowG * Hc + (colG - Hc)] = v;
                }
            }
        }
    }
}

// ---------------------------------------------------------------------------
// Batched logits GEMM: out[(b*STEPS+t)*V+n] = h_all[t*256+b,:] . Wfc[n,:] + bfc[n]
// (zeroed where lengths[b] <= t). BM=128, BN=64, LDS-transpose epilogue with
// float4 stores. m-major grid (46, 157).
// ---------------------------------------------------------------------------
__global__ __launch_bounds__(256) void logits_gemm(
    const unsigned short* __restrict__ A,   // h_all [5888][512]
    const unsigned short* __restrict__ Bm,  // WfcB [10000][512]
    const float* __restrict__ bias,         // bfc
    float* __restrict__ out,
    const int* __restrict__ lengths)
{
    constexpr int BM = 128, BN = 64, BK = 64, LDT = BK + 8, K = Hc;
    constexpr int EP = 68;  // epilogue fp32 row stride
    __shared__ __align__(16) unsigned char smraw[BM * EP * 4];  // 34816 B (>27648 gemm)
    unsigned short* sA = (unsigned short*)smraw;
    unsigned short* sB = sA + BM * LDT;
    float* sE = (float*)smraw;

    const int tid = threadIdx.x;
    const int wid = tid >> 6, lane = tid & 63;
    const int wm = wid >> 1, wn = wid & 1;
    const int m0 = blockIdx.x * BM, n0 = blockIdx.y * BN;
    constexpr int FM = 4, FN = 2;

    floatx4 acc[FM][FN];
    #pragma unroll
    for (int i = 0; i < FM; i++)
        #pragma unroll
        for (int j = 0; j < FN; j++)
            #pragma unroll
            for (int r = 0; r < 4; r++) acc[i][j][r] = 0.f;

    const int lm = lane & 15, half = lane >> 4;

    for (int k0 = 0; k0 < K; k0 += BK) {
        #pragma unroll
        for (int ii = 0; ii < 4; ii++) {           // A: 128 rows x 8 chunks
            int i = tid + ii * 256;
            int row = i >> 3, ck = i & 7;
            ushort8 v = *reinterpret_cast<const ushort8*>(
                A + (size_t)(m0 + row) * K + k0 + ck * 8);
            *reinterpret_cast<ushort8*>(sA + row * LDT + ck * 8) = v;
        }
        #pragma unroll
        for (int ii = 0; ii < 2; ii++) {           // B: 64 rows x 8 chunks
            int i = tid + ii * 256;
            int row = i >> 3, ck = i & 7;
            int gn = n0 + row;
            ushort8 v;
            if (gn < Vc) {
                v = *reinterpret_cast<const ushort8*>(Bm + (size_t)gn * K + k0 + ck * 8);
            } else {
                #pragma unroll
                for (int j = 0; j < 8; j++) v[j] = 0;
            }
            *reinterpret_cast<ushort8*>(sB + row * LDT + ck * 8) = v;
        }
        __syncthreads();

        #pragma unroll
        for (int kk = 0; kk < BK; kk += 32) {
            bf16x8 af[FM], bfb[FN];
            #pragma unroll
            for (int fm = 0; fm < FM; fm++)
                af[fm] = *reinterpret_cast<const bf16x8*>(
                    sA + (wm * 64 + fm * 16 + lm) * LDT + kk + half * 8);
            #pragma unroll
            for (int fn = 0; fn < FN; fn++)
                bfb[fn] = *reinterpret_cast<const bf16x8*>(
                    sB + (wn * 32 + fn * 16 + lm) * LDT + kk + half * 8);
            #pragma unroll
            for (int fm = 0; fm < FM; fm++)
                #pragma unroll
                for (int fn = 0; fn < FN; fn++)
                    acc[fm][fn] = __builtin_amdgcn_mfma_f32_16x16x32_bf16(
                        af[fm], bfb[fn], acc[fm][fn], 0, 0, 0);
        }
        __syncthreads();
    }

    // dump acc to LDS fp32 (C-layout), then row-contiguous float4 stores
    const int quad = lane >> 4;
    #pragma unroll
    for (int fm = 0; fm < FM; fm++)
        #pragma unroll
        for (int fn = 0; fn < FN; fn++)
            #pragma unroll
            for (int r = 0; r < 4; r++)
                sE[(wm * 64 + fm * 16 + quad * 4 + r) * EP + wn * 32 + fn * 16 + lm]
                    = acc[fm][fn][r];
    __syncthreads();

    const int r = tid >> 1, hh = tid & 1;
    const int rowG = m0 + r;
    const int tt = rowG >> 8, bb = rowG & 255;
    const bool act = lengths[bb] > tt;
    const size_t base = ((size_t)bb * STEPS + tt) * Vc;
    #pragma unroll
    for (int j = 0; j < 8; j++) {
        int col = n0 + hh * 32 + j * 4;
        if (col < Vc) {
            float4 v = *reinterpret_cast<const float4*>(sE + r * EP + hh * 32 + j * 4);
            float4 bv = *reinterpret_cast<const float4*>(bias + col);
            v.x = act ? v.x + bv.x : 0.f;
            v.y = act ? v.y + bv.y : 0.f;
            v.z = act ? v.z + bv.z : 0.f;
            v.w = act ? v.w + bv.w : 0.f;
            *reinterpret_cast<float4*>(out + base + col) = v;
        }
    }
}

// ---------------------------------------------------------------------------
// Light attention: hp from hg[b, 2048:2560] (+bh); scores over fproj; softmax;
// ctx -> xcur ctx slice.
// ---------------------------------------------------------------------------
__global__ __launch_bounds__(256) void attn_kernel(
    const unsigned short* __restrict__ fproj,
    const unsigned short* __restrict__ featsB,
    const float* __restrict__ hg,       // [256][2560]
    const float* __restrict__ bh,
    const float* __restrict__ Ws,
    const float* __restrict__ bs,
    unsigned short* __restrict__ xcur)  // [256][2304] = [emb | ctx]
{
    const int b = blockIdx.x, tid = threadIdx.x;
    const int wid = tid >> 6, lane = tid & 63;
    __shared__ float s_hp[Acn];
    __shared__ float s_sc[64];

    #pragma unroll
    for (int i = tid; i < Acn; i += 256)
        s_hp[i] = hg[(size_t)b * NG + 2048 + i] + bh[i];
    __syncthreads();

    float ws8[8], hp8[8];
    {
        const float* wsb = Ws + lane * 8;
        #pragma unroll
        for (int j = 0; j < 8; j++) { ws8[j] = wsb[j]; hp8[j] = s_hp[lane * 8 + j]; }
    }
    for (int r = wid; r < Rc; r += 4) {
        ushort8 e = *reinterpret_cast<const ushort8*>(
            fproj + ((size_t)b * Rc + r) * Acn + lane * 8);
        float sum = 0.f;
        #pragma unroll
        for (int j = 0; j < 8; j++)
            sum += ws8[j] * tanhf(bf2f(e[j]) + hp8[j]);
        #pragma unroll
        for (int off = 32; off > 0; off >>= 1) sum += __shfl_down(sum, off);
        if (lane == 0) s_sc[r] = sum + bs[0];
    }
    __syncthreads();

    if (wid == 0) {
        float v = (lane < Rc) ? s_sc[lane] : -3.0e38f;
        float mx = v;
        #pragma unroll
        for (int off = 32; off > 0; off >>= 1) mx = fmaxf(mx, __shfl_xor(mx, off));
        float e = (lane < Rc) ? __expf(v - mx) : 0.f;
        float sm = e;
        #pragma unroll
        for (int off = 32; off > 0; off >>= 1) sm += __shfl_xor(sm, off);
        if (lane < Rc) s_sc[lane] = e / sm;
    }
    __syncthreads();

    const int f0 = tid * 8;
    float c[8];
    #pragma unroll
    for (int j = 0; j < 8; j++) c[j] = 0.f;
    #pragma unroll 7
    for (int r = 0; r < Rc; r++) {
        float a = s_sc[r];
        ushort8 v = *reinterpret_cast<const ushort8*>(
            featsB + ((size_t)(b * Rc + r)) * Fc + f0);
        #pragma unroll
        for (int j = 0; j < 8; j++) c[j] += a * bf2f(v[j]);
    }
    ushort8 o;
    #pragma unroll
    for (int j = 0; j < 8; j++) o[j] = f2bf(c[j]);
    *reinterpret_cast<ushort8*>(xcur + (size_t)b * XE + Ec + f0) = o;
}

// ---------------------------------------------------------------------------
// Fused x-GEMM + LSTM pointwise. 512 threads, in-block split-K=2.
// Block (mx, jy): b in [mx*64, mx*64+64), j in [jy*8, jy*8+8).
// B rows staged gate-interleaved: staged row r <-> W row (r>>3)*512 + j0 + (r&7),
// so all 4 gate quadrants of each (b,j) are in-block.
// Epilogue: gates = ctx/emb-GEMM + hg + b_ih + b_hh -> LSTM -> c/h update,
// h_all record, next-step emb gather into xnext (blocks jy==0 only).
// ---------------------------------------------------------------------------
__global__ __launch_bounds__(512) void xlstm_kernel(
    const unsigned short* __restrict__ xA,   // [256][2304] this step
    unsigned short* __restrict__ xnext,      // next step buffer (emb region)
    const unsigned short* __restrict__ Wih,  // [2048][2304]
    const float* __restrict__ hg,            // [256][2560]
    const float* __restrict__ b_ih,
    const float* __restrict__ b_hh,
    float* __restrict__ c_state,
    unsigned short* __restrict__ h_buf,
    unsigned short* __restrict__ h_all,
    const int* __restrict__ lengths,
    const int* __restrict__ ids,
    const unsigned short* __restrict__ embB,
    int t)
{
    constexpr int BK = 64, LDT = BK + 8;      // 72
    constexpr int KS = XE / 2;                // 1152 per k-slice
    constexpr int GEP = 36;                   // gate LDS row stride (fp32)
    __shared__ __align__(16) unsigned char smraw[2 * 96 * LDT * 2];  // 27648 B
    unsigned short* sU = (unsigned short*)smraw;
    float* sG = (float*)smraw;                // 2*64*36 fp32 = 18432 B (reuse)

    const int tid = threadIdx.x;
    const int wid = tid >> 6, lane = tid & 63;
    const int ks = wid >> 2, wm = (wid >> 1) & 1, wn = wid & 1;
    const int m0 = blockIdx.x * 64, j0 = blockIdx.y * 8;
    const int lm = lane & 15, half = lane >> 4;
    const int tloc = tid & 255;               // within k-slice half

    unsigned short* sA = sU + ks * 96 * LDT;
    unsigned short* sB = sA + 64 * LDT;

    floatx4 acc[2];
    #pragma unroll
    for (int i = 0; i < 2; i++)
        #pragma unroll
        for (int r = 0; r < 4; r++) acc[i][r] = 0.f;

    const size_t kbase = (size_t)ks * KS;

    for (int k0 = 0; k0 < KS; k0 += BK) {
        #pragma unroll
        for (int ii = 0; ii < 2; ii++) {      // A: 64 rows x 8 chunks / 256 thr
            int i = tloc + ii * 256;
            int row = i >> 3, ck = i & 7;
            ushort8 v = *reinterpret_cast<const ushort8*>(
                xA + (size_t)(m0 + row) * XE + kbase + k0 + ck * 8);
            *reinterpret_cast<ushort8*>(sA + row * LDT + ck * 8) = v;
        }
        {                                      // B: 32 rows x 8 chunks / 256 thr
            int row = tloc >> 3, ck = tloc & 7;
            int gn = (row >> 3) * 512 + j0 + (row & 7);
            ushort8 v = *reinterpret_cast<const ushort8*>(
                Wih + (size_t)gn * XE + kbase + k0 + ck * 8);
            *reinterpret_cast<ushort8*>(sB + row * LDT + ck * 8) = v;
        }
        __syncthreads();

        #pragma unroll
        for (int kk = 0; kk < BK; kk += 32) {
            bf16x8 af[2], bfb;
            #pragma unroll
            for (int fm = 0; fm < 2; fm++)
                af[fm] = *reinterpret_cast<const bf16x8*>(
                    sA + (wm * 32 + fm * 16 + lm) * LDT + kk + half * 8);
            bfb = *reinterpret_cast<const bf16x8*>(
                sB + (wn * 16 + lm) * LDT + kk + half * 8);
            #pragma unroll
            for (int fm = 0; fm < 2; fm++)
                acc[fm] = __builtin_amdgcn_mfma_f32_16x16x32_bf16(
                    af[fm], bfb, acc[fm], 0, 0, 0);
        }
        __syncthreads();
    }

    // dump per-slice partials to LDS fp32
    const int quad = lane >> 4;
    #pragma unroll
    for (int fm = 0; fm < 2; fm++)
        #pragma unroll
        for (int r = 0; r < 4; r++)
            sG[ks * 64 * GEP + (wm * 32 + fm * 16 + quad * 4 + r) * GEP
               + wn * 16 + lm] = acc[fm][r];
    __syncthreads();

    // pointwise LSTM: thread -> (b-local, j-local)
    {
        const int bl = tid >> 3, jj = tid & 7;
        const int b = m0 + bl, j = j0 + jj;
        float G[4];
        #pragma unroll
        for (int g = 0; g < 4; g++) {
            int c = g * 8 + jj;
            int gc = g * 512 + j;
            G[g] = sG[bl * GEP + c] + sG[64 * GEP + bl * GEP + c]
                 + hg[(size_t)b * NG + gc] + b_ih[gc] + b_hh[gc];
        }
        float i_ = 1.f / (1.f + __expf(-G[0]));
        float f_ = 1.f / (1.f + __expf(-G[1]));
        float gv = tanhf(G[2]);
        float o_ = 1.f / (1.f + __expf(-G[3]));
        float c_old = c_state[(size_t)b * Hc + j];
        float ct = f_ * c_old + i_ * gv;
        float ht = o_ * tanhf(ct);
        unsigned short hb = f2bf(ht);
        h_all[((size_t)t * Bc + b) * Hc + j] = hb;
        if (lengths[b] > t) {
            c_state[(size_t)b * Hc + j] = ct;
            h_buf[(size_t)b * Hc + j] = hb;
        }
    }

    // next-step embedding gather (one block column only)
    if (blockIdx.y == 0 && t + 1 < STEPS) {
        for (int idx = tid; idx < 64 * 32; idx += 512) {
            int bl2 = idx >> 5, ch = idx & 31;
            int b2 = m0 + bl2;
            int id = ids[b2 * Lc + (t + 1)];
            *reinterpret_cast<ushort8*>(xnext + (size_t)b2 * XE + ch * 8) =
                *reinterpret_cast<const ushort8*>(embB + (size_t)id * Ec + ch * 8);
        }
    }
}

// ---------------------------------------------------------------------------
// Setup: mean over R of featsB + emb[:,0] gather into x0.
// ---------------------------------------------------------------------------
__global__ __launch_bounds__(256) void mean_emb_kernel(
    const unsigned short* __restrict__ featsB,
    const int* __restrict__ ids,
    const unsigned short* __restrict__ embB,
    unsigned short* __restrict__ meanB,
    unsigned short* __restrict__ x0)
{
    const int b = blockIdx.x, tid = threadIdx.x;
    const int f0 = tid * 8;
    float s[8];
    #pragma unroll
    for (int j = 0; j < 8; j++) s[j] = 0.f;
    #pragma unroll 7
    for (int r = 0; r < Rc; r++) {
        ushort8 v = *reinterpret_cast<const ushort8*>(
            featsB + ((size_t)(b * Rc + r)) * Fc + f0);
        #pragma unroll
        for (int j = 0; j < 8; j++) s[j] += bf2f(v[j]);
    }
    ushort8 o;
    #pragma unroll
    for (int j = 0; j < 8; j++) o[j] = f2bf(s[j] * (1.f / (float)Rc));
    *reinterpret_cast<ushort8*>(meanB + (size_t)b * Fc + f0) = o;
    if (tid < Ec) {
        int id = ids[b * Lc + 0];
        x0[(size_t)b * XE + tid] = embB[(size_t)id * Ec + tid];
    }
}

// ---------------------------------------------------------------------------
extern "C" void kernel_launch(void* const* d_in, const int* in_sizes, int n_in,
                              void* d_out, int out_size, void* d_ws, size_t ws_size,
                              hipStream_t stream)
{
    const float* feats = (const float*)d_in[0];
    const int*   ids   = (const int*)d_in[1];
    const int*   lens  = (const int*)d_in[2];
    const float* embW  = (const float*)d_in[3];
    const float* Wf    = (const float*)d_in[4];
    const float* bf_   = (const float*)d_in[5];
    const float* Wh    = (const float*)d_in[6];
    const float* bh    = (const float*)d_in[7];
    const float* Ws_   = (const float*)d_in[8];
    const float* bs_   = (const float*)d_in[9];
    const float* W_ih  = (const float*)d_in[10];
    const float* b_ih  = (const float*)d_in[11];
    const float* W_hh  = (const float*)d_in[12];
    const float* b_hh  = (const float*)d_in[13];
    const float* Wfc   = (const float*)d_in[14];
    const float* bfc   = (const float*)d_in[15];
    const float* Wi_h  = (const float*)d_in[16];
    const float* bi_h  = (const float*)d_in[17];
    const float* Wi_c  = (const float*)d_in[18];
    const float* bi_c  = (const float*)d_in[19];

    char* ws = (char*)d_ws;
    auto alloc_us = [&](size_t n) { unsigned short* p = (unsigned short*)ws; ws += n * 2; return p; };
    auto alloc_f  = [&](size_t n) { float* p = (float*)ws; ws += n * 4; return p; };

    unsigned short* featsB = alloc_us((size_t)Bc * Rc * Fc);
    unsigned short* embB   = alloc_us((size_t)Vc * Ec);
    unsigned short* WfB    = alloc_us((size_t)Acn * Fc);
    unsigned short* WfcB   = alloc_us((size_t)Vc * Hc);
    unsigned short* WihB   = alloc_us((size_t)2048 * XE);
    unsigned short* Whg    = alloc_us((size_t)NG * Hc);   // [W_hh ; Wh]
    unsigned short* WihB2  = alloc_us((size_t)Hc * Fc);   // Wi_h
    unsigned short* WicB   = alloc_us((size_t)Hc * Fc);   // Wi_c
    unsigned short* meanB  = alloc_us((size_t)Bc * Fc);
    unsigned short* fproj  = alloc_us((size_t)Bc * Rc * Acn);
    unsigned short* xbuf0  = alloc_us((size_t)Bc * XE);
    unsigned short* xbuf1  = alloc_us((size_t)Bc * XE);
    unsigned short* h_buf  = alloc_us((size_t)Bc * Hc);
    unsigned short* h_all  = alloc_us((size_t)STEPS * Bc * Hc);
    float*          c_st   = alloc_f((size_t)Bc * Hc);
    float*          hg     = alloc_f((size_t)Bc * NG);
    float*          outF   = (float*)d_out;

    CvtArgs ca;
    ca.src[0] = feats; ca.dst[0] = featsB;
    ca.src[1] = embW;  ca.dst[1] = embB;
    ca.src[2] = Wf;    ca.dst[2] = WfB;
    ca.src[3] = Wfc;   ca.dst[3] = WfcB;
    ca.src[4] = W_ih;  ca.dst[4] = WihB;
    ca.src[5] = W_hh;  ca.dst[5] = Whg;                       // rows 0..2047
    ca.src[6] = Wh;    ca.dst[6] = Whg + (size_t)2048 * Hc;   // rows 2048..2559
    ca.src[7] = Wi_h;  ca.dst[7] = WihB2;
    ca.src[8] = Wi_c;  ca.dst[8] = WicB;
    convert_all<<<CVT_BLOCKS, 256, 0, stream>>>(ca);

    mean_emb_kernel<<<Bc, 256, 0, stream>>>(featsB, ids, embB, meanB, xbuf0);

    // h0/c0 init: M=256, N=1024 (Wi_h|Wi_c), K=2048, tanh epilogue
    gemm_tn<64, 64, 64, 2><<<dim3(4, 16), 256, 0, stream>>>(
        meanB, Fc, WihB2, Fc, WicB, bi_h, bi_c,
        nullptr, h_buf, c_st, 2 * Hc, Fc);

    // f_proj: M=12544, N=512, K=2048 -> bf16
    gemm_tn<128, 128, 64, 1><<<dim3(98, 4), 256, 0, stream>>>(
        featsB, Fc, WfB, Fc, nullptr, bf_, nullptr,
        nullptr, fproj, nullptr, Acn, Fc);

    for (int t = 0; t < STEPS; t++) {
        unsigned short* xcur  = (t & 1) ? xbuf1 : xbuf0;
        unsigned short* xnext = (t & 1) ? xbuf0 : xbuf1;

        // hgemm: hg = h @ [W_hh;Wh]^T : M=256, N=2560, K=512 -> 320 blocks
        gemm_tn<64, 32, 64, 0><<<dim3(4, 80), 256, 0, stream>>>(
            h_buf, Hc, Whg, Hc, nullptr, nullptr, nullptr,
            hg, nullptr, nullptr, NG, Hc);

        attn_kernel<<<Bc, 256, 0, stream>>>(fproj, featsB, hg, bh, Ws_, bs_, xcur);

        // fused x-GEMM + LSTM: grid (4, 64), 512 threads
        xlstm_kernel<<<dim3(4, 64), 512, 0, stream>>>(
            xcur, xnext, WihB, hg, b_ih, b_hh, c_st, h_buf, h_all,
            lens, ids, embB, t);
    }

    // batched logits: M=5888, N=10000, K=512, m-major grid
    logits_gemm<<<dim3(46, 157), 256, 0, stream>>>(
        h_all, WfcB, bfc, outF, lens);
}